// Round 11
// baseline (319.252 us; speedup 1.0000x reference)
//
#include <hip/hip_runtime.h>

typedef __bf16 bf16;
typedef __attribute__((ext_vector_type(2))) bf16 bf16x2;
typedef __attribute__((ext_vector_type(4))) bf16 bf16x4;
typedef __attribute__((ext_vector_type(8))) bf16 bf16x8;
typedef __attribute__((ext_vector_type(4))) float f32x4;
typedef __attribute__((ext_vector_type(16))) float f32x16;
typedef __attribute__((ext_vector_type(4))) int i32x4;
typedef __attribute__((ext_vector_type(2))) int i32x2;

#define MFMA_BF16(a, b, c) __builtin_amdgcn_mfma_f32_16x16x32_bf16((a), (b), (c), 0, 0, 0)
#define MFMA32(a, b, c)    __builtin_amdgcn_mfma_f32_32x32x16_bf16((a), (b), (c), 0, 0, 0)

constexpr int S_LEN = 2048;
constexpr int EMB   = 1024;
constexpr int NHEAD = 16;
constexpr int HDIM  = 64;
constexpr int BATCH = 4;
constexpr int NTOK  = BATCH * S_LEN;   // 8192

// async global->LDS, 16B per lane (m97 pattern: LDS dest must be uniform base + lane*16)
__device__ __forceinline__ void gload_lds16(const bf16* g, bf16* l) {
    __builtin_amdgcn_global_load_lds(
        (const __attribute__((address_space(1))) void*)g,
        (__attribute__((address_space(3))) void*)l, 16, 0, 0);
}

// pack two f32 -> one dword of 2 bf16
__device__ __forceinline__ int pkbf(float a, float b) {
    bf16x2 t; t[0] = (bf16)a; t[1] = (bf16)b;
    return __builtin_bit_cast(int, t);
}

// half-wave swap primitive (T12). r[0] = {a[0:31], b[0:31]}, r[1] = {a[32:63], b[32:63]}.
#if __has_builtin(__builtin_amdgcn_permlane32_swap)
__device__ __forceinline__ i32x2 permswap(int a, int b) {
    return __builtin_amdgcn_permlane32_swap(a, b, false, false);
}
#else
__device__ __forceinline__ i32x2 permswap(int a, int b) {
    int as = __shfl_xor(a, 32);
    int bs = __shfl_xor(b, 32);
    int hx_ = (threadIdx.x >> 5) & 1;
    i32x2 r;
    r[0] = hx_ ? bs : a;
    r[1] = hx_ ? b : as;
    return r;
}
#endif

// ---------------------------------------------------------------------------
// fp32 -> bf16 elementwise convert (n4 = n/4)
// ---------------------------------------------------------------------------
__global__ __launch_bounds__(256)
void cvt_f32_bf16(const float* __restrict__ src, bf16* __restrict__ dst, int n4) {
    int i = blockIdx.x * 256 + threadIdx.x;
    if (i < n4) {
        f32x4 v = ((const f32x4*)src)[i];
        bf16x4 o;
        o[0] = (bf16)v[0]; o[1] = (bf16)v[1]; o[2] = (bf16)v[2]; o[3] = (bf16)v[3];
        ((bf16x4*)dst)[i] = o;
    }
}

// 4 weight matrices (1M f32 each) in one launch; dst contiguous [4][EMB*EMB]
__global__ __launch_bounds__(256)
void cvt_w4(const float* __restrict__ s0, const float* __restrict__ s1,
            const float* __restrict__ s2, const float* __restrict__ s3,
            bf16* __restrict__ dst) {
    const int a = blockIdx.y;
    const float* s = a == 0 ? s0 : (a == 1 ? s1 : (a == 2 ? s2 : s3));
    int i = blockIdx.x * 256 + threadIdx.x;           // n4 = EMB*EMB/4 = 262144
    f32x4 v = ((const f32x4*)s)[i];
    bf16x4 o;
    o[0] = (bf16)v[0]; o[1] = (bf16)v[1]; o[2] = (bf16)v[2]; o[3] = (bf16)v[3];
    ((bf16x4*)(dst + (size_t)a * EMB * EMB))[i] = o;
}

// ---------------------------------------------------------------------------
// 256x256 TRIPLE-BUFFERED BK=32 NT GEMM, 2-tiles-ahead prefetch, counted vmcnt.
//
// Rate ladder measured this session (chip rate during a full 256-block round):
//   128^2 2-phase (R7) ~414 TF; 128x256 4-phase (R9) ~365; 256^2 4-phase
//   counted (R8) ~612. 256^2 wins on MFMA-per-barrier; R8's deficiency was
//   prefetch depth (~2-3 phases) vs L3 latency + 1 blk/CU convoy.
// This version: BK=32 full tiles (A,B each 256x32 = 16KB), THREE buffers
// (96KB LDS) -> stage tile t+2 while computing t: cover ~= 2 tile-times
// (~2500cy) >> L3 latency (~900cy). One barrier + one counted wait per tile.
//
// Hazard ledger (oldest-first vmcnt, m135): at iter t we issue stage(t+2)
// [4 loads]; outstanding = stage(t+1)[4] + stage(t+2)[4] = 8; end-of-iter
// vmcnt(4) drains stage(t+1) (read next iter), leaves stage(t+2). ✓
// WAR: stage(t+2) writes buf[(t+2)%3], last read at iter t-1; those ds_reads
// completed before t-1's barrier; stage issued after. ✓
// Tail: t=30 -> no stage, vmcnt(0) drains stage(31); t=31 -> no wait.
// All barriers under t-uniform conditions (no divergent-barrier deadlock).
//
// 512 thr = 8 waves (2M x 4N), per-wave C 128x64, acc[8][4] (128 VGPR),
// 32 MFMA per tile per wave. Slot swizzle s ^= (row>>1)&3 on stage-source
// AND read (rule #21, carried from R8 verified).
// XCD-chunked remap: xcd = fb&7 owns 4 consecutive M-tiles (A-chunk 2MB,
// L2-resident). fused=1 (384 blocks): y in [0,12), seg=y>>2, n0=(y&3)*256,
// V scatters to Vt[b,h,d,s]. fused=0 (128 blocks): y in [0,4), fp32 out.
// ---------------------------------------------------------------------------
__global__ __launch_bounds__(512)
void gemm256(const bf16* __restrict__ A,
             const bf16* __restrict__ W0, const bf16* __restrict__ W1, const bf16* __restrict__ W2,
             const float* __restrict__ b0, const float* __restrict__ b1, const float* __restrict__ b2,
             void* __restrict__ d0, void* __restrict__ d1, void* __restrict__ d2,
             int fused, float q_scale)
{
    __shared__ bf16 la[3][256 * 32];   // 16KB each
    __shared__ bf16 lb[3][256 * 32];   // 16KB each -> 96KB total

    // XCD-chunked bijective remap: xcd owns M-tiles [xcd*4, xcd*4+4)
    const int fb  = blockIdx.x;
    const int xcd = fb & 7;
    const int loc = fb >> 3;                 // fused: [0,48); else [0,16)
    const int xi  = xcd * 4 + (loc & 3);     // M-tile [0,32)
    const int y   = loc >> 2;                // fused: [0,12); else [0,4)

    int seg, mode, n0;
    if (fused) { seg = y >> 2; n0 = (y & 3) * 256; mode = (seg == 2) ? 1 : 0; }
    else       { seg = 0;      n0 = y * 256;        mode = 2; }
    const bf16*  W    = seg == 0 ? W0 : (seg == 1 ? W1 : W2);
    const float* bias = seg == 0 ? b0 : (seg == 1 ? b1 : b2);
    void*        C    = seg == 0 ? d0 : (seg == 1 ? d1 : d2);
    const float  osc  = (fused && seg == 0) ? q_scale : 1.0f;

    const int tid  = threadIdx.x;          // 0..511
    const int lane = tid & 63;
    const int w    = tid >> 6;             // wave 0..7
    const int wr   = w >> 2;               // M half -> rows wr*128..+127
    const int wc   = w & 3;                // N quarter -> cols wc*64..+63
    const int quad = lane >> 4;
    const int l16  = lane & 15;
    const int m0   = xi * 256;

    // stage one 256x32 tile (16KB = 1024 x 16B; 2 loads/thread/operand).
    // row = idx>>2 in [0,256), slot = idx&3; source slot pre-swizzled.
#define STAGE_T(BI, T) {                                                            \
    _Pragma("unroll") for (int c_ = 0; c_ < 2; ++c_) {                              \
        int idx_ = c_ * 512 + tid;                                                  \
        int r_ = idx_ >> 2, s_ = idx_ & 3;                                          \
        int co_ = (T) * 32 + ((s_ ^ ((r_ >> 1) & 3)) << 3);                         \
        gload_lds16(A + (size_t)(m0 + r_) * EMB + co_, &la[BI][idx_ * 8]);          \
        gload_lds16(W + (size_t)(n0 + r_) * EMB + co_, &lb[BI][idx_ * 8]);          \
    } }

    f32x4 acc[8][4] = {};

    // prologue: stage tiles 0,1 (8 loads); drain tile 0, leave tile 1 in flight
    STAGE_T(0, 0)
    STAGE_T(1, 1)
    asm volatile("s_waitcnt vmcnt(4)" ::: "memory");
    __builtin_amdgcn_s_barrier();
    __builtin_amdgcn_sched_barrier(0);

    int cur = 0;
    for (int t = 0; t < 32; ++t) {
        int sb = cur + 2; if (sb >= 3) sb -= 3;
        if (t + 2 < 32) STAGE_T(sb, t + 2)

        // frag reads (swizzled) + 32 MFMA on buffer cur
        bf16x8 afr[8], bfr[4];
        #pragma unroll
        for (int i = 0; i < 8; ++i) {
            int m_ = wr * 128 + i * 16 + l16;
            afr[i] = *(const bf16x8*)&la[cur][m_ * 32 + ((quad ^ ((m_ >> 1) & 3)) << 3)];
        }
        #pragma unroll
        for (int j = 0; j < 4; ++j) {
            int n_ = wc * 64 + j * 16 + l16;
            bfr[j] = *(const bf16x8*)&lb[cur][n_ * 32 + ((quad ^ ((n_ >> 1) & 3)) << 3)];
        }
        __builtin_amdgcn_s_setprio(1);
        #pragma unroll
        for (int i = 0; i < 8; ++i)
            #pragma unroll
            for (int j = 0; j < 4; ++j)
                acc[i][j] = MFMA_BF16(afr[i], bfr[j], acc[i][j]);
        __builtin_amdgcn_s_setprio(0);

        // counted drain: stage(t+1) must be resident for next iter; stage(t+2) stays in flight
        if (t + 2 < 32)      asm volatile("s_waitcnt vmcnt(4)" ::: "memory");
        else if (t + 1 < 32) asm volatile("s_waitcnt vmcnt(0)" ::: "memory");
        if (t + 1 < 32) {
            __builtin_amdgcn_s_barrier();
            __builtin_amdgcn_sched_barrier(0);
        }
        cur = (cur + 1 == 3) ? 0 : cur + 1;
    }
#undef STAGE_T

    // epilogue: per 16x16 frag, C row = quad*4+r, col = l16 (m89-verified; R8-passed)
    #pragma unroll
    for (int ii = 0; ii < 8; ++ii) {
        #pragma unroll
        for (int j = 0; j < 4; ++j) {
            int col = n0 + wc * 64 + j * 16 + l16;
            float bv = bias[col];
            int row0 = m0 + wr * 128 + ii * 16 + quad * 4;
            if (mode == 1) {
                int bb = row0 >> 11, s0 = row0 & 2047;
                int hh = col >> 6,   d  = col & 63;
                bf16x4 pk;
                #pragma unroll
                for (int r = 0; r < 4; ++r) pk[r] = (bf16)(acc[ii][j][r] + bv);
                *(bf16x4*)((bf16*)C + (size_t)((bb * NHEAD + hh) * HDIM + d) * S_LEN + s0) = pk;
            } else if (mode == 0) {
                #pragma unroll
                for (int r = 0; r < 4; ++r)
                    ((bf16*)C)[(size_t)(row0 + r) * EMB + col] = (bf16)((acc[ii][j][r] + bv) * osc);
            } else {
                #pragma unroll
                for (int r = 0; r < 4; ++r)
                    ((float*)C)[(size_t)(row0 + r) * EMB + col] = acc[ii][j][r] + bv;
            }
        }
    }
}

// ---------------------------------------------------------------------------
// Flash attention — FROZEN (verified 92-94us in R7-R9).
// 8 waves x 32 q-rows, KVBLK=64 double-buffered in LDS via global_load_lds.
// ---------------------------------------------------------------------------
__global__ __launch_bounds__(512)
void flash_attn(const bf16* __restrict__ qg, const bf16* __restrict__ kg,
                const bf16* __restrict__ vtg, const int* __restrict__ maskg,
                bf16* __restrict__ ctx)
{
    __shared__ bf16  klds[2][64 * 64];
    __shared__ bf16  vlds[2][64 * 64];
    __shared__ bf16  bias_lds[2048];
    __shared__ float stat_lds[8][32];

    const int fb  = blockIdx.x;
    const int xcd = fb & 7;
    const int rr  = fb >> 3;
    const int qi  = rr & 7;
    const int gg  = rr >> 3;
    const int g   = gg * 8 + xcd;
    const int h   = g & 15;
    const int b   = g >> 4;
    const int q0  = qi * 256;

    const int tid  = threadIdx.x;
    const int lane = tid & 63;
    const int w    = tid >> 6;
    const int l32  = lane & 31;
    const int hx   = lane >> 5;

    const int srow  = tid >> 3;
    const int sslot = (tid & 7) ^ (srow & 7);

    int ok;
    {
        int i = tid * 4;
        i32x4 mv = *(const i32x4*)(maskg + b * S_LEN + i);
        bf16x4 bb;
        ok = 1;
        #pragma unroll
        for (int r = 0; r < 4; ++r) {
            ok &= (mv[r] != 0);
            bb[r] = mv[r] ? (bf16)0.f : (bf16)(-3.0e38f);
        }
        *(bf16x4*)&bias_lds[i] = bb;
    }
    const int allvalid = __syncthreads_and(ok);

    bf16x8 qf[4];
    {
        const bf16* qrow = qg + (size_t)(b * S_LEN + q0 + w * 32 + l32) * EMB + h * HDIM + hx * 8;
        qf[0] = *(const bf16x8*)(qrow);
        qf[1] = *(const bf16x8*)(qrow + 16);
        qf[2] = *(const bf16x8*)(qrow + 32);
        qf[3] = *(const bf16x8*)(qrow + 48);
    }

    const bf16* kgb = kg  + (size_t)b * S_LEN * EMB + h * HDIM;
    const bf16* vgb = vtg + (size_t)((b * NHEAD + h) * HDIM) * S_LEN;

    float mrow = -1e30f, lpart = 0.f;
    f32x16 o0, o1;
    #pragma unroll
    for (int r = 0; r < 16; ++r) { o0[r] = 0.f; o1[r] = 0.f; }

#define STAGE(BUF, KT) {                                                            \
    gload_lds16(kgb + (size_t)((KT) * 64 + srow) * EMB + sslot * 8,                 \
                &klds[BUF][tid * 8]);                                               \
    gload_lds16(vgb + (size_t)srow * S_LEN + (KT) * 64 + sslot * 8,                 \
                &vlds[BUF][tid * 8]);                                               \
}

#define LDSK(CUR, ROW, SB) (*(const bf16x8*)((const char*)&klds[CUR][0] + ((ROW) << 7) + ((((SB) ^ ((ROW) & 7))) << 4)))
#define LDSV(CUR, ROW, SB) (*(const bf16x8*)((const char*)&vlds[CUR][0] + ((ROW) << 7) + ((((SB) ^ ((ROW) & 7))) << 4)))

#define SUBTILE(CUR, KT, KK) {                                                      \
    f32x16 s_;                                                                      \
    _Pragma("unroll") for (int r_ = 0; r_ < 16; ++r_) s_[r_] = 0.f;                 \
    const int krow_ = (KK) * 32 + l32;                                              \
    __builtin_amdgcn_s_setprio(1);                                                  \
    s_ = MFMA32(LDSK(CUR, krow_, 0 * 2 + hx), qf[0], s_);                           \
    s_ = MFMA32(LDSK(CUR, krow_, 1 * 2 + hx), qf[1], s_);                           \
    s_ = MFMA32(LDSK(CUR, krow_, 2 * 2 + hx), qf[2], s_);                           \
    s_ = MFMA32(LDSK(CUR, krow_, 3 * 2 + hx), qf[3], s_);                           \
    __builtin_amdgcn_s_setprio(0);                                                  \
    if (!allvalid) {                                                                \
        _Pragma("unroll") for (int s4_ = 0; s4_ < 4; ++s4_) {                       \
            bf16x4 b4_ = *(const bf16x4*)&bias_lds[(KT) * 64 + (KK) * 32 + s4_ * 8 + hx * 4]; \
            _Pragma("unroll") for (int t_ = 0; t_ < 4; ++t_)                        \
                s_[4 * s4_ + t_] += (float)b4_[t_];                                 \
        }                                                                           \
    }                                                                               \
    float rmax_ = s_[0];                                                            \
    _Pragma("unroll") for (int r_ = 1; r_ < 16; ++r_) rmax_ = fmaxf(rmax_, s_[r_]); \
    rmax_ = fmaxf(rmax_, __shfl_xor(rmax_, 32));                                    \
    if (!__all(rmax_ <= mrow + 8.f)) {                                              \
        float mnew_  = fmaxf(mrow, rmax_);                                          \
        float alpha_ = __builtin_amdgcn_exp2f(mrow - mnew_);                        \
        mrow = mnew_; lpart *= alpha_;                                              \
        if (hx == 0) stat_lds[w][l32] = alpha_;                                     \
        _Pragma("unroll") for (int s4_ = 0; s4_ < 4; ++s4_) {                       \
            f32x4 a4_ = *(const f32x4*)&stat_lds[w][s4_ * 8 + hx * 4];              \
            _Pragma("unroll") for (int t_ = 0; t_ < 4; ++t_) {                      \
                o0[4 * s4_ + t_] *= a4_[t_]; o1[4 * s4_ + t_] *= a4_[t_];           \
            }                                                                       \
        }                                                                           \
    }                                                                               \
    bf16x8 pa0, pa1;                                                                \
    {                                                                               \
        float p_[8];                                                                \
        _Pragma("unroll") for (int r_ = 0; r_ < 8; ++r_) {                          \
            p_[r_] = __builtin_amdgcn_exp2f(s_[r_] - mrow); lpart += p_[r_];        \
        }                                                                           \
        i32x2 r0_ = permswap(pkbf(p_[0], p_[1]), pkbf(p_[4], p_[5]));               \
        i32x2 r1_ = permswap(pkbf(p_[2], p_[3]), pkbf(p_[6], p_[7]));               \
        i32x4 fw_; fw_[0] = r0_[0]; fw_[1] = r1_[0]; fw_[2] = r0_[1]; fw_[3] = r1_[1]; \
        pa0 = __builtin_bit_cast(bf16x8, fw_);                                      \
    }                                                                               \
    {                                                                               \
        float p_[8];                                                                \
        _Pragma("unroll") for (int r_ = 0; r_ < 8; ++r_) {                          \
            p_[r_] = __builtin_amdgcn_exp2f(s_[8 + r_] - mrow); lpart += p_[r_];    \
        }                                                                           \
        i32x2 r0_ = permswap(pkbf(p_[0], p_[1]), pkbf(p_[4], p_[5]));               \
        i32x2 r1_ = permswap(pkbf(p_[2], p_[3]), pkbf(p_[6], p_[7]));               \
        i32x4 fw_; fw_[0] = r0_[0]; fw_[1] = r1_[0]; fw_[2] = r0_[1]; fw_[3] = r1_[1]; \
        pa1 = __builtin_bit_cast(bf16x8, fw_);                                      \
    }                                                                               \
    __builtin_amdgcn_s_setprio(1);                                                  \
    o0 = MFMA32(pa0, LDSV(CUR, 0 * 32 + l32, (KK) * 4 + 0 * 2 + hx), o0);           \
    o1 = MFMA32(pa0, LDSV(CUR, 1 * 32 + l32, (KK) * 4 + 0 * 2 + hx), o1);           \
    o0 = MFMA32(pa1, LDSV(CUR, 0 * 32 + l32, (KK) * 4 + 1 * 2 + hx), o0);           \
    o1 = MFMA32(pa1, LDSV(CUR, 1 * 32 + l32, (KK) * 4 + 1 * 2 + hx), o1);           \
    __builtin_amdgcn_s_setprio(0);                                                  \
}

    STAGE(0, 0)
    __syncthreads();

    for (int kt = 0; kt < 32; ++kt) {
        const int cur = kt & 1;
        if (kt + 1 < 32) STAGE(cur ^ 1, kt + 1)
        SUBTILE(cur, kt, 0)
        SUBTILE(cur, kt, 1)
        __syncthreads();
    }

#undef SUBTILE
#undef LDSK
#undef LDSV
#undef STAGE

    float lrow = lpart + __shfl_xor(lpart, 32);
    float inv  = lrow > 0.f ? 1.f / lrow : 0.f;
    if (hx == 0) stat_lds[w][l32] = inv;
    #pragma unroll
    for (int s4 = 0; s4 < 4; ++s4) {
        f32x4 i4 = *(const f32x4*)&stat_lds[w][s4 * 8 + hx * 4];
        #pragma unroll
        for (int t = 0; t < 4; ++t) {
            size_t row = (size_t)(b * S_LEN + q0 + w * 32 + s4 * 8 + hx * 4 + t);
            bf16* cp = ctx + row * EMB + h * HDIM + l32;
            cp[0]  = (bf16)(o0[4 * s4 + t] * i4[t]);
            cp[32] = (bf16)(o1[4 * s4 + t] * i4[t]);
        }
    }
}

extern "C" void kernel_launch(void* const* d_in, const int* in_sizes, int n_in,
                              void* d_out, int out_size, void* d_ws, size_t ws_size,
                              hipStream_t stream)
{
    const float* x   = (const float*)d_in[0];
    const int*  mask = (const int*)d_in[1];
    const float* Wq  = (const float*)d_in[2];
    const float* bq  = (const float*)d_in[3];
    const float* Wk  = (const float*)d_in[4];
    const float* bk  = (const float*)d_in[5];
    const float* Wv  = (const float*)d_in[6];
    const float* bv  = (const float*)d_in[7];
    const float* Wo  = (const float*)d_in[8];
    const float* bo  = (const float*)d_in[9];
    (void)in_sizes; (void)n_in; (void)out_size; (void)ws_size;

    const size_t me = (size_t)NTOK * EMB;    // 8.4M
    const size_t we = (size_t)EMB * EMB;     // 1M
    bf16* xb  = (bf16*)d_ws;
    bf16* qb  = xb  + me;
    bf16* kb  = qb  + me;
    bf16* vt  = kb  + me;     // V transposed [b,h,d,s]
    bf16* wqb = vt  + me;     // [4][we] contiguous: wq, wk, wv, wo
    bf16* wkb = wqb + we;
    bf16* wvb = wkb + we;
    bf16* wob = wvb + we;
    bf16* cx  = xb;           // alias: xb consumed by qkv gemm before flash writes cx

    cvt_f32_bf16<<<(int)(me / 4 / 256), 256, 0, stream>>>(x, xb, (int)(me / 4));
    cvt_w4<<<dim3((int)(we / 4 / 256), 4), 256, 0, stream>>>(Wq, Wk, Wv, Wo, wqb);

    // q_scale = 1/sqrt(HDIM) * log2(e), folded into Q so flash softmax is scale-free
    gemm256<<<dim3(8 * 48), 512, 0, stream>>>(
        xb, wqb, wkb, wvb, bq, bk, bv, qb, kb, vt, 1, 0.18033688011112042f);

    flash_attn<<<dim3(512), 512, 0, stream>>>(qb, kb, vt, mask, cx);

    gemm256<<<dim3(8 * 16), 512, 0, stream>>>(
        cx, wob, wob, wob, bo, bo, bo, d_out, d_out, d_out, 0, 1.0f);
}

// Round 12
// 316.448 us; speedup vs baseline: 1.0089x; 1.0089x over previous
//
#include <hip/hip_runtime.h>

typedef __bf16 bf16;
typedef __attribute__((ext_vector_type(2))) bf16 bf16x2;
typedef __attribute__((ext_vector_type(4))) bf16 bf16x4;
typedef __attribute__((ext_vector_type(8))) bf16 bf16x8;
typedef __attribute__((ext_vector_type(4))) float f32x4;
typedef __attribute__((ext_vector_type(16))) float f32x16;
typedef __attribute__((ext_vector_type(4))) int i32x4;
typedef __attribute__((ext_vector_type(2))) int i32x2;

#define MFMA_BF16(a, b, c) __builtin_amdgcn_mfma_f32_16x16x32_bf16((a), (b), (c), 0, 0, 0)
#define MFMA32(a, b, c)    __builtin_amdgcn_mfma_f32_32x32x16_bf16((a), (b), (c), 0, 0, 0)

constexpr int S_LEN = 2048;
constexpr int EMB   = 1024;
constexpr int NHEAD = 16;
constexpr int HDIM  = 64;
constexpr int BATCH = 4;
constexpr int NTOK  = BATCH * S_LEN;   // 8192

// async global->LDS, 16B per lane (m97 pattern: LDS dest must be uniform base + lane*16)
__device__ __forceinline__ void gload_lds16(const bf16* g, bf16* l) {
    __builtin_amdgcn_global_load_lds(
        (const __attribute__((address_space(1))) void*)g,
        (__attribute__((address_space(3))) void*)l, 16, 0, 0);
}

// pack two f32 -> one dword of 2 bf16
__device__ __forceinline__ int pkbf(float a, float b) {
    bf16x2 t; t[0] = (bf16)a; t[1] = (bf16)b;
    return __builtin_bit_cast(int, t);
}

// half-wave swap primitive (T12). r[0] = {a[0:31], b[0:31]}, r[1] = {a[32:63], b[32:63]}.
#if __has_builtin(__builtin_amdgcn_permlane32_swap)
__device__ __forceinline__ i32x2 permswap(int a, int b) {
    return __builtin_amdgcn_permlane32_swap(a, b, false, false);
}
#else
__device__ __forceinline__ i32x2 permswap(int a, int b) {
    int as = __shfl_xor(a, 32);
    int bs = __shfl_xor(b, 32);
    int hx_ = (threadIdx.x >> 5) & 1;
    i32x2 r;
    r[0] = hx_ ? bs : a;
    r[1] = hx_ ? b : as;
    return r;
}
#endif

// ---------------------------------------------------------------------------
// fp32 -> bf16 elementwise convert (n4 = n/4)
// ---------------------------------------------------------------------------
__global__ __launch_bounds__(256)
void cvt_f32_bf16(const float* __restrict__ src, bf16* __restrict__ dst, int n4) {
    int i = blockIdx.x * 256 + threadIdx.x;
    if (i < n4) {
        f32x4 v = ((const f32x4*)src)[i];
        bf16x4 o;
        o[0] = (bf16)v[0]; o[1] = (bf16)v[1]; o[2] = (bf16)v[2]; o[3] = (bf16)v[3];
        ((bf16x4*)dst)[i] = o;
    }
}

// 4 weight matrices (1M f32 each) in one launch; dst contiguous [4][EMB*EMB]
__global__ __launch_bounds__(256)
void cvt_w4(const float* __restrict__ s0, const float* __restrict__ s1,
            const float* __restrict__ s2, const float* __restrict__ s3,
            bf16* __restrict__ dst) {
    const int a = blockIdx.y;
    const float* s = a == 0 ? s0 : (a == 1 ? s1 : (a == 2 ? s2 : s3));
    int i = blockIdx.x * 256 + threadIdx.x;           // n4 = EMB*EMB/4 = 262144
    f32x4 v = ((const f32x4*)s)[i];
    bf16x4 o;
    o[0] = (bf16)v[0]; o[1] = (bf16)v[1]; o[2] = (bf16)v[2]; o[3] = (bf16)v[3];
    ((bf16x4*)(dst + (size_t)a * EMB * EMB))[i] = o;
}

// ---------------------------------------------------------------------------
// 256x256 DOUBLE-BUFFERED BK=32 NT GEMM — 2 blocks/CU (the occupancy fix).
//
// R11 lesson (counters): 96KB LDS triple-buffer = 1 block/CU; all 8 waves
// convoy at the per-tile vmcnt+barrier with NO other block to fill the
// stall (MfmaUtil 21%, VALUBusy 12%, Occupancy 16%). Deeper prefetch can't
// fix a convoy. m97/m114/m132: cross-block overlap (>=2 blocks/CU) is what
// hides staging latency, and trading occupancy for barrier-amortization
// loses. So: BK=32, TWO buffers (2 x 32KB = 64KB) -> 2 blocks/CU; simple
// m97 2-phase {STAGE(next); read frags; 32 MFMA; __syncthreads()}. The
// barrier's full vmcnt drain is covered by the co-resident block's MFMA.
// QKV's 384 blocks are ALL resident at once (no rounds, no tail).
//
// 512 thr = 8 waves (2M x 4N), per-wave C 128x64, acc[8][4], 32 MFMA/tile.
// Slot swizzle s ^= (row>>1)&3 on stage-source AND read (rule #21,
// R8/R11-verified: bank-conflict 0, passed). XCD-chunked remap: xcd = fb&7
// owns 4 consecutive M-tiles (A-chunk L2-resident).
// fused=1 (384 blocks): y in [0,12), seg=y>>2, n0=(y&3)*256, V scatters to
// Vt[b,h,d,s]. fused=0 (128 blocks): y in [0,4), fp32 out.
// ---------------------------------------------------------------------------
__global__ __launch_bounds__(512)
void gemm256(const bf16* __restrict__ A,
             const bf16* __restrict__ W0, const bf16* __restrict__ W1, const bf16* __restrict__ W2,
             const float* __restrict__ b0, const float* __restrict__ b1, const float* __restrict__ b2,
             void* __restrict__ d0, void* __restrict__ d1, void* __restrict__ d2,
             int fused, float q_scale)
{
    __shared__ bf16 la[2][256 * 32];   // 16KB each
    __shared__ bf16 lb[2][256 * 32];   // 16KB each -> 64KB total => 2 blocks/CU

    // XCD-chunked bijective remap: xcd owns M-tiles [xcd*4, xcd*4+4)
    const int fb  = blockIdx.x;
    const int xcd = fb & 7;
    const int loc = fb >> 3;                 // fused: [0,48); else [0,16)
    const int xi  = xcd * 4 + (loc & 3);     // M-tile [0,32)
    const int y   = loc >> 2;                // fused: [0,12); else [0,4)

    int seg, mode, n0;
    if (fused) { seg = y >> 2; n0 = (y & 3) * 256; mode = (seg == 2) ? 1 : 0; }
    else       { seg = 0;      n0 = y * 256;        mode = 2; }
    const bf16*  W    = seg == 0 ? W0 : (seg == 1 ? W1 : W2);
    const float* bias = seg == 0 ? b0 : (seg == 1 ? b1 : b2);
    void*        C    = seg == 0 ? d0 : (seg == 1 ? d1 : d2);
    const float  osc  = (fused && seg == 0) ? q_scale : 1.0f;

    const int tid  = threadIdx.x;          // 0..511
    const int lane = tid & 63;
    const int w    = tid >> 6;             // wave 0..7
    const int wr   = w >> 2;               // M half -> rows wr*128..+127
    const int wc   = w & 3;                // N quarter -> cols wc*64..+63
    const int quad = lane >> 4;
    const int l16  = lane & 15;
    const int m0   = xi * 256;

    // stage one 256x32 tile (16KB = 1024 x 16B; 2 loads/thread/operand).
    // row = idx>>2 in [0,256), slot = idx&3; source slot pre-swizzled.
#define STAGE_T(BI, T) {                                                            \
    _Pragma("unroll") for (int c_ = 0; c_ < 2; ++c_) {                              \
        int idx_ = c_ * 512 + tid;                                                  \
        int r_ = idx_ >> 2, s_ = idx_ & 3;                                          \
        int co_ = (T) * 32 + ((s_ ^ ((r_ >> 1) & 3)) << 3);                         \
        gload_lds16(A + (size_t)(m0 + r_) * EMB + co_, &la[BI][idx_ * 8]);          \
        gload_lds16(W + (size_t)(n0 + r_) * EMB + co_, &lb[BI][idx_ * 8]);          \
    } }

    f32x4 acc[8][4] = {};

    // prologue: stage tile 0, drain, barrier
    STAGE_T(0, 0)
    __syncthreads();

    for (int t = 0; t < 32; ++t) {
        const int cur = t & 1;
        if (t + 1 < 32) STAGE_T(cur ^ 1, t + 1)   // issue next-tile loads FIRST

        // frag reads (swizzled) + 32 MFMA on buffer cur
        bf16x8 afr[8], bfr[4];
        #pragma unroll
        for (int i = 0; i < 8; ++i) {
            int m_ = wr * 128 + i * 16 + l16;
            afr[i] = *(const bf16x8*)&la[cur][m_ * 32 + ((quad ^ ((m_ >> 1) & 3)) << 3)];
        }
        #pragma unroll
        for (int j = 0; j < 4; ++j) {
            int n_ = wc * 64 + j * 16 + l16;
            bfr[j] = *(const bf16x8*)&lb[cur][n_ * 32 + ((quad ^ ((n_ >> 1) & 3)) << 3)];
        }
        __builtin_amdgcn_s_setprio(1);
        #pragma unroll
        for (int i = 0; i < 8; ++i)
            #pragma unroll
            for (int j = 0; j < 4; ++j)
                acc[i][j] = MFMA_BF16(afr[i], bfr[j], acc[i][j]);
        __builtin_amdgcn_s_setprio(0);

        // drains this iter's stage loads + all waves done reading buf[cur];
        // the co-resident block's MFMA covers this stall (m114 overlap)
        __syncthreads();
    }
#undef STAGE_T

    // epilogue: per 16x16 frag, C row = quad*4+r, col = l16 (m89-verified; R8/R11-passed)
    #pragma unroll
    for (int ii = 0; ii < 8; ++ii) {
        #pragma unroll
        for (int j = 0; j < 4; ++j) {
            int col = n0 + wc * 64 + j * 16 + l16;
            float bv = bias[col];
            int row0 = m0 + wr * 128 + ii * 16 + quad * 4;
            if (mode == 1) {
                int bb = row0 >> 11, s0 = row0 & 2047;
                int hh = col >> 6,   d  = col & 63;
                bf16x4 pk;
                #pragma unroll
                for (int r = 0; r < 4; ++r) pk[r] = (bf16)(acc[ii][j][r] + bv);
                *(bf16x4*)((bf16*)C + (size_t)((bb * NHEAD + hh) * HDIM + d) * S_LEN + s0) = pk;
            } else if (mode == 0) {
                #pragma unroll
                for (int r = 0; r < 4; ++r)
                    ((bf16*)C)[(size_t)(row0 + r) * EMB + col] = (bf16)((acc[ii][j][r] + bv) * osc);
            } else {
                #pragma unroll
                for (int r = 0; r < 4; ++r)
                    ((float*)C)[(size_t)(row0 + r) * EMB + col] = acc[ii][j][r] + bv;
            }
        }
    }
}

// ---------------------------------------------------------------------------
// Flash attention — FROZEN (verified 92-94us in R7-R9).
// 8 waves x 32 q-rows, KVBLK=64 double-buffered in LDS via global_load_lds.
// ---------------------------------------------------------------------------
__global__ __launch_bounds__(512)
void flash_attn(const bf16* __restrict__ qg, const bf16* __restrict__ kg,
                const bf16* __restrict__ vtg, const int* __restrict__ maskg,
                bf16* __restrict__ ctx)
{
    __shared__ bf16  klds[2][64 * 64];
    __shared__ bf16  vlds[2][64 * 64];
    __shared__ bf16  bias_lds[2048];
    __shared__ float stat_lds[8][32];

    const int fb  = blockIdx.x;
    const int xcd = fb & 7;
    const int rr  = fb >> 3;
    const int qi  = rr & 7;
    const int gg  = rr >> 3;
    const int g   = gg * 8 + xcd;
    const int h   = g & 15;
    const int b   = g >> 4;
    const int q0  = qi * 256;

    const int tid  = threadIdx.x;
    const int lane = tid & 63;
    const int w    = tid >> 6;
    const int l32  = lane & 31;
    const int hx   = lane >> 5;

    const int srow  = tid >> 3;
    const int sslot = (tid & 7) ^ (srow & 7);

    int ok;
    {
        int i = tid * 4;
        i32x4 mv = *(const i32x4*)(maskg + b * S_LEN + i);
        bf16x4 bb;
        ok = 1;
        #pragma unroll
        for (int r = 0; r < 4; ++r) {
            ok &= (mv[r] != 0);
            bb[r] = mv[r] ? (bf16)0.f : (bf16)(-3.0e38f);
        }
        *(bf16x4*)&bias_lds[i] = bb;
    }
    const int allvalid = __syncthreads_and(ok);

    bf16x8 qf[4];
    {
        const bf16* qrow = qg + (size_t)(b * S_LEN + q0 + w * 32 + l32) * EMB + h * HDIM + hx * 8;
        qf[0] = *(const bf16x8*)(qrow);
        qf[1] = *(const bf16x8*)(qrow + 16);
        qf[2] = *(const bf16x8*)(qrow + 32);
        qf[3] = *(const bf16x8*)(qrow + 48);
    }

    const bf16* kgb = kg  + (size_t)b * S_LEN * EMB + h * HDIM;
    const bf16* vgb = vtg + (size_t)((b * NHEAD + h) * HDIM) * S_LEN;

    float mrow = -1e30f, lpart = 0.f;
    f32x16 o0, o1;
    #pragma unroll
    for (int r = 0; r < 16; ++r) { o0[r] = 0.f; o1[r] = 0.f; }

#define STAGE(BUF, KT) {                                                            \
    gload_lds16(kgb + (size_t)((KT) * 64 + srow) * EMB + sslot * 8,                 \
                &klds[BUF][tid * 8]);                                               \
    gload_lds16(vgb + (size_t)srow * S_LEN + (KT) * 64 + sslot * 8,                 \
                &vlds[BUF][tid * 8]);                                               \
}

#define LDSK(CUR, ROW, SB) (*(const bf16x8*)((const char*)&klds[CUR][0] + ((ROW) << 7) + ((((SB) ^ ((ROW) & 7))) << 4)))
#define LDSV(CUR, ROW, SB) (*(const bf16x8*)((const char*)&vlds[CUR][0] + ((ROW) << 7) + ((((SB) ^ ((ROW) & 7))) << 4)))

#define SUBTILE(CUR, KT, KK) {                                                      \
    f32x16 s_;                                                                      \
    _Pragma("unroll") for (int r_ = 0; r_ < 16; ++r_) s_[r_] = 0.f;                 \
    const int krow_ = (KK) * 32 + l32;                                              \
    __builtin_amdgcn_s_setprio(1);                                                  \
    s_ = MFMA32(LDSK(CUR, krow_, 0 * 2 + hx), qf[0], s_);                           \
    s_ = MFMA32(LDSK(CUR, krow_, 1 * 2 + hx), qf[1], s_);                           \
    s_ = MFMA32(LDSK(CUR, krow_, 2 * 2 + hx), qf[2], s_);                           \
    s_ = MFMA32(LDSK(CUR, krow_, 3 * 2 + hx), qf[3], s_);                           \
    __builtin_amdgcn_s_setprio(0);                                                  \
    if (!allvalid) {                                                                \
        _Pragma("unroll") for (int s4_ = 0; s4_ < 4; ++s4_) {                       \
            bf16x4 b4_ = *(const bf16x4*)&bias_lds[(KT) * 64 + (KK) * 32 + s4_ * 8 + hx * 4]; \
            _Pragma("unroll") for (int t_ = 0; t_ < 4; ++t_)                        \
                s_[4 * s4_ + t_] += (float)b4_[t_];                                 \
        }                                                                           \
    }                                                                               \
    float rmax_ = s_[0];                                                            \
    _Pragma("unroll") for (int r_ = 1; r_ < 16; ++r_) rmax_ = fmaxf(rmax_, s_[r_]); \
    rmax_ = fmaxf(rmax_, __shfl_xor(rmax_, 32));                                    \
    if (!__all(rmax_ <= mrow + 8.f)) {                                              \
        float mnew_  = fmaxf(mrow, rmax_);                                          \
        float alpha_ = __builtin_amdgcn_exp2f(mrow - mnew_);                        \
        mrow = mnew_; lpart *= alpha_;                                              \
        if (hx == 0) stat_lds[w][l32] = alpha_;                                     \
        _Pragma("unroll") for (int s4_ = 0; s4_ < 4; ++s4_) {                       \
            f32x4 a4_ = *(const f32x4*)&stat_lds[w][s4_ * 8 + hx * 4];              \
            _Pragma("unroll") for (int t_ = 0; t_ < 4; ++t_) {                      \
                o0[4 * s4_ + t_] *= a4_[t_]; o1[4 * s4_ + t_] *= a4_[t_];           \
            }                                                                       \
        }                                                                           \
    }                                                                               \
    bf16x8 pa0, pa1;                                                                \
    {                                                                               \
        float p_[8];                                                                \
        _Pragma("unroll") for (int r_ = 0; r_ < 8; ++r_) {                          \
            p_[r_] = __builtin_amdgcn_exp2f(s_[r_] - mrow); lpart += p_[r_];        \
        }                                                                           \
        i32x2 r0_ = permswap(pkbf(p_[0], p_[1]), pkbf(p_[4], p_[5]));               \
        i32x2 r1_ = permswap(pkbf(p_[2], p_[3]), pkbf(p_[6], p_[7]));               \
        i32x4 fw_; fw_[0] = r0_[0]; fw_[1] = r1_[0]; fw_[2] = r0_[1]; fw_[3] = r1_[1]; \
        pa0 = __builtin_bit_cast(bf16x8, fw_);                                      \
    }                                                                               \
    {                                                                               \
        float p_[8];                                                                \
        _Pragma("unroll") for (int r_ = 0; r_ < 8; ++r_) {                          \
            p_[r_] = __builtin_amdgcn_exp2f(s_[8 + r_] - mrow); lpart += p_[r_];    \
        }                                                                           \
        i32x2 r0_ = permswap(pkbf(p_[0], p_[1]), pkbf(p_[4], p_[5]));               \
        i32x2 r1_ = permswap(pkbf(p_[2], p_[3]), pkbf(p_[6], p_[7]));               \
        i32x4 fw_; fw_[0] = r0_[0]; fw_[1] = r1_[0]; fw_[2] = r0_[1]; fw_[3] = r1_[1]; \
        pa1 = __builtin_bit_cast(bf16x8, fw_);                                      \
    }                                                                               \
    __builtin_amdgcn_s_setprio(1);                                                  \
    o0 = MFMA32(pa0, LDSV(CUR, 0 * 32 + l32, (KK) * 4 + 0 * 2 + hx), o0);           \
    o1 = MFMA32(pa0, LDSV(CUR, 1 * 32 + l32, (KK) * 4 + 0 * 2 + hx), o1);           \
    o0 = MFMA32(pa1, LDSV(CUR, 0 * 32 + l32, (KK) * 4 + 1 * 2 + hx), o0);           \
    o1 = MFMA32(pa1, LDSV(CUR, 1 * 32 + l32, (KK) * 4 + 1 * 2 + hx), o1);           \
    __builtin_amdgcn_s_setprio(0);                                                  \
}

    STAGE(0, 0)
    __syncthreads();

    for (int kt = 0; kt < 32; ++kt) {
        const int cur = kt & 1;
        if (kt + 1 < 32) STAGE(cur ^ 1, kt + 1)
        SUBTILE(cur, kt, 0)
        SUBTILE(cur, kt, 1)
        __syncthreads();
    }

#undef SUBTILE
#undef LDSK
#undef LDSV
#undef STAGE

    float lrow = lpart + __shfl_xor(lpart, 32);
    float inv  = lrow > 0.f ? 1.f / lrow : 0.f;
    if (hx == 0) stat_lds[w][l32] = inv;
    #pragma unroll
    for (int s4 = 0; s4 < 4; ++s4) {
        f32x4 i4 = *(const f32x4*)&stat_lds[w][s4 * 8 + hx * 4];
        #pragma unroll
        for (int t = 0; t < 4; ++t) {
            size_t row = (size_t)(b * S_LEN + q0 + w * 32 + s4 * 8 + hx * 4 + t);
            bf16* cp = ctx + row * EMB + h * HDIM + l32;
            cp[0]  = (bf16)(o0[4 * s4 + t] * i4[t]);
            cp[32] = (bf16)(o1[4 * s4 + t] * i4[t]);
        }
    }
}

extern "C" void kernel_launch(void* const* d_in, const int* in_sizes, int n_in,
                              void* d_out, int out_size, void* d_ws, size_t ws_size,
                              hipStream_t stream)
{
    const float* x   = (const float*)d_in[0];
    const int*  mask = (const int*)d_in[1];
    const float* Wq  = (const float*)d_in[2];
    const float* bq  = (const float*)d_in[3];
    const float* Wk  = (const float*)d_in[4];
    const float* bk  = (const float*)d_in[5];
    const float* Wv  = (const float*)d_in[6];
    const float* bv  = (const float*)d_in[7];
    const float* Wo  = (const float*)d_in[8];
    const float* bo  = (const float*)d_in[9];
    (void)in_sizes; (void)n_in; (void)out_size; (void)ws_size;

    const size_t me = (size_t)NTOK * EMB;    // 8.4M
    const size_t we = (size_t)EMB * EMB;     // 1M
    bf16* xb  = (bf16*)d_ws;
    bf16* qb  = xb  + me;
    bf16* kb  = qb  + me;
    bf16* vt  = kb  + me;     // V transposed [b,h,d,s]
    bf16* wqb = vt  + me;     // [4][we] contiguous: wq, wk, wv, wo
    bf16* wkb = wqb + we;
    bf16* wvb = wkb + we;
    bf16* wob = wvb + we;
    bf16* cx  = xb;           // alias: xb consumed by qkv gemm before flash writes cx

    cvt_f32_bf16<<<(int)(me / 4 / 256), 256, 0, stream>>>(x, xb, (int)(me / 4));
    cvt_w4<<<dim3((int)(we / 4 / 256), 4), 256, 0, stream>>>(Wq, Wk, Wv, Wo, wqb);

    // q_scale = 1/sqrt(HDIM) * log2(e), folded into Q so flash softmax is scale-free
    gemm256<<<dim3(8 * 48), 512, 0, stream>>>(
        xb, wqb, wkb, wvb, bq, bk, bv, qb, kb, vt, 1, 0.18033688011112042f);

    flash_attn<<<dim3(512), 512, 0, stream>>>(qb, kb, vt, mask, cx);

    gemm256<<<dim3(8 * 16), 512, 0, stream>>>(
        cx, wob, wob, wob, bo, bo, bo, d_out, d_out, d_out, 0, 1.0f);
}

// Round 14
// 277.564 us; speedup vs baseline: 1.1502x; 1.1401x over previous
//
#include <hip/hip_runtime.h>

typedef __bf16 bf16;
typedef __attribute__((ext_vector_type(2))) bf16 bf16x2;
typedef __attribute__((ext_vector_type(4))) bf16 bf16x4;
typedef __attribute__((ext_vector_type(8))) bf16 bf16x8;
typedef __attribute__((ext_vector_type(4))) float f32x4;
typedef __attribute__((ext_vector_type(16))) float f32x16;
typedef __attribute__((ext_vector_type(4))) int i32x4;
typedef __attribute__((ext_vector_type(2))) int i32x2;

#define MFMA_BF16(a, b, c) __builtin_amdgcn_mfma_f32_16x16x32_bf16((a), (b), (c), 0, 0, 0)
#define MFMA32(a, b, c)    __builtin_amdgcn_mfma_f32_32x32x16_bf16((a), (b), (c), 0, 0, 0)

constexpr int S_LEN = 2048;
constexpr int EMB   = 1024;
constexpr int NHEAD = 16;
constexpr int HDIM  = 64;
constexpr int BATCH = 4;
constexpr int NTOK  = BATCH * S_LEN;   // 8192

// async global->LDS, 16B per lane (m97 pattern: LDS dest must be uniform base + lane*16)
__device__ __forceinline__ void gload_lds16(const bf16* g, bf16* l) {
    __builtin_amdgcn_global_load_lds(
        (const __attribute__((address_space(1))) void*)g,
        (__attribute__((address_space(3))) void*)l, 16, 0, 0);
}

// pack two f32 -> one dword of 2 bf16
__device__ __forceinline__ int pkbf(float a, float b) {
    bf16x2 t; t[0] = (bf16)a; t[1] = (bf16)b;
    return __builtin_bit_cast(int, t);
}

// half-wave swap primitive (T12). r[0] = {a[0:31], b[0:31]}, r[1] = {a[32:63], b[32:63]}.
#if __has_builtin(__builtin_amdgcn_permlane32_swap)
__device__ __forceinline__ i32x2 permswap(int a, int b) {
    return __builtin_amdgcn_permlane32_swap(a, b, false, false);
}
#else
__device__ __forceinline__ i32x2 permswap(int a, int b) {
    int as = __shfl_xor(a, 32);
    int bs = __shfl_xor(b, 32);
    int hx_ = (threadIdx.x >> 5) & 1;
    i32x2 r;
    r[0] = hx_ ? bs : a;
    r[1] = hx_ ? b : as;
    return r;
}
#endif

// ---------------------------------------------------------------------------
// fp32 -> bf16 elementwise convert (n4 = n/4)
// ---------------------------------------------------------------------------
__global__ __launch_bounds__(256)
void cvt_f32_bf16(const float* __restrict__ src, bf16* __restrict__ dst, int n4) {
    int i = blockIdx.x * 256 + threadIdx.x;
    if (i < n4) {
        f32x4 v = ((const f32x4*)src)[i];
        bf16x4 o;
        o[0] = (bf16)v[0]; o[1] = (bf16)v[1]; o[2] = (bf16)v[2]; o[3] = (bf16)v[3];
        ((bf16x4*)dst)[i] = o;
    }
}

// 4 weight matrices (1M f32 each) in one launch; dst contiguous [4][EMB*EMB]
__global__ __launch_bounds__(256)
void cvt_w4(const float* __restrict__ s0, const float* __restrict__ s1,
            const float* __restrict__ s2, const float* __restrict__ s3,
            bf16* __restrict__ dst) {
    const int a = blockIdx.y;
    const float* s = a == 0 ? s0 : (a == 1 ? s1 : (a == 2 ? s2 : s3));
    int i = blockIdx.x * 256 + threadIdx.x;           // n4 = EMB*EMB/4 = 262144
    f32x4 v = ((const f32x4*)s)[i];
    bf16x4 o;
    o[0] = (bf16)v[0]; o[1] = (bf16)v[1]; o[2] = (bf16)v[2]; o[3] = (bf16)v[3];
    ((bf16x4*)(dst + (size_t)a * EMB * EMB))[i] = o;
}

// ---------------------------------------------------------------------------
// NT GEMM, m97 structure — R7 body VERBATIM (session-best total), plus
// XCD-chunked flat-grid remap (T1), the one measured-positive lever R7 lacked.
//
// Ledger truth (R8-R12): the 256x256 tile family (4-phase counted / 3-buf /
// 2-buf 2-phase) landed QKV 86-97us in every variant and NEVER beat R7's
// total. R7's 128^2: 64B LDS rows are naturally bank-spread, 4-wave blocks
// at ~3 blocks/CU give real cross-block overlap (m114). Its one deficiency:
// round-robin dispatch served its ~768MB of staged A/W re-reads cross-XCD
// from L3. Fix: xcd = fb&7 owns xi in [xcd*8, xcd*8+8) -> per-XCD A-chunk
// 2MB L2-resident across all 24 y-reuses.
//
// fused=1: 1536 blocks flat = 8 xcd x {8 xi-local x 24 y}; seg = y>>3 picks
// {Q,K,V}; n0 = (y&7)*128; V scatters to Vt[b,h,d,s]. fused=0: 512 blocks
// flat = 8 x {8 x 8 y}; fp32 out. q_scale folded into Q (seg==0).
// ---------------------------------------------------------------------------
__global__ __launch_bounds__(256)
void gemm_bt(const bf16* __restrict__ A,
             const bf16* __restrict__ W0, const bf16* __restrict__ W1, const bf16* __restrict__ W2,
             const float* __restrict__ b0, const float* __restrict__ b1, const float* __restrict__ b2,
             void* __restrict__ d0, void* __restrict__ d1, void* __restrict__ d2,
             int fused, float q_scale)
{
    __shared__ bf16 al[128 * 32];
    __shared__ bf16 bl[128 * 32];

    // XCD-chunked bijective remap: xcd owns xi in [xcd*8, xcd*8+8)
    const int fb  = blockIdx.x;
    const int xcd = fb & 7;
    const int loc = fb >> 3;                 // fused: [0,192); else [0,64)
    const int xi  = xcd * 8 + (loc & 7);     // M-tile [0,64)
    const int y   = loc >> 3;                // fused: [0,24); else [0,8)

    int seg, mode, n0;
    if (fused) { seg = y >> 3; n0 = (y & 7) * 128; mode = (seg == 2) ? 1 : 0; }
    else       { seg = 0;      n0 = y * 128;        mode = 2; }
    const bf16*  W    = seg == 0 ? W0 : (seg == 1 ? W1 : W2);
    const float* bias = seg == 0 ? b0 : (seg == 1 ? b1 : b2);
    void*        C    = seg == 0 ? d0 : (seg == 1 ? d1 : d2);
    const float  osc  = (fused && seg == 0) ? q_scale : 1.0f;

    const int tid  = threadIdx.x;
    const int lane = tid & 63;
    const int w    = tid >> 6;
    const int quad = lane >> 4;
    const int l16  = lane & 15;
    const int wm   = (w >> 1) * 64;
    const int wn   = (w & 1) * 64;
    const int m0   = xi * 128;

    f32x4 acc[4][4] = {};

    for (int k0 = 0; k0 < EMB; k0 += 32) {
        #pragma unroll
        for (int c = 0; c < 2; ++c) {
            int idx = c * 256 + tid;            // LDS addr = idx*16B: uniform base + lane*16 per wave
            int row = idx >> 2, kc = idx & 3;
            gload_lds16(A + (size_t)(m0 + row) * EMB + k0 + kc * 8, &al[idx * 8]);
            gload_lds16(W + (size_t)(n0 + row) * EMB + k0 + kc * 8, &bl[idx * 8]);
        }
        __syncthreads();

        bf16x8 afrag[4], bfrag[4];
        #pragma unroll
        for (int t = 0; t < 4; ++t)
            afrag[t] = *(const bf16x8*)&al[(wm + t * 16 + l16) * 32 + quad * 8];
        #pragma unroll
        for (int t = 0; t < 4; ++t)
            bfrag[t] = *(const bf16x8*)&bl[(wn + t * 16 + l16) * 32 + quad * 8];

        #pragma unroll
        for (int mt = 0; mt < 4; ++mt)
            #pragma unroll
            for (int nt = 0; nt < 4; ++nt)
                acc[mt][nt] = MFMA_BF16(afrag[mt], bfrag[nt], acc[mt][nt]);

        __syncthreads();
    }

    // epilogue: C-layout row = quad*4+r, col = l16 (m89-verified)
    #pragma unroll
    for (int mt = 0; mt < 4; ++mt) {
        #pragma unroll
        for (int nt = 0; nt < 4; ++nt) {
            int col = n0 + wn + nt * 16 + l16;
            float bv = bias[col];
            int row0 = m0 + wm + mt * 16 + quad * 4;
            if (mode == 1) {
                int bb = row0 >> 11, s0 = row0 & 2047;
                int hh = col >> 6,   d  = col & 63;
                bf16x4 pk;
                #pragma unroll
                for (int r = 0; r < 4; ++r) pk[r] = (bf16)(acc[mt][nt][r] + bv);
                *(bf16x4*)((bf16*)C + (size_t)((bb * NHEAD + hh) * HDIM + d) * S_LEN + s0) = pk;
            } else if (mode == 0) {
                #pragma unroll
                for (int r = 0; r < 4; ++r)
                    ((bf16*)C)[(size_t)(row0 + r) * EMB + col] = (bf16)((acc[mt][nt][r] + bv) * osc);
            } else {
                #pragma unroll
                for (int r = 0; r < 4; ++r)
                    ((float*)C)[(size_t)(row0 + r) * EMB + col] = acc[mt][nt][r] + bv;
            }
        }
    }
}

// ---------------------------------------------------------------------------
// Flash attention — FROZEN (verified 92-94us in R7-R12).
// 8 waves x 32 q-rows, KVBLK=64 double-buffered in LDS via global_load_lds.
// ---------------------------------------------------------------------------
__global__ __launch_bounds__(512)
void flash_attn(const bf16* __restrict__ qg, const bf16* __restrict__ kg,
                const bf16* __restrict__ vtg, const int* __restrict__ maskg,
                bf16* __restrict__ ctx)
{
    __shared__ bf16  klds[2][64 * 64];
    __shared__ bf16  vlds[2][64 * 64];
    __shared__ bf16  bias_lds[2048];
    __shared__ float stat_lds[8][32];

    const int fb  = blockIdx.x;
    const int xcd = fb & 7;
    const int rr  = fb >> 3;
    const int qi  = rr & 7;
    const int gg  = rr >> 3;
    const int g   = gg * 8 + xcd;
    const int h   = g & 15;
    const int b   = g >> 4;
    const int q0  = qi * 256;

    const int tid  = threadIdx.x;
    const int lane = tid & 63;
    const int w    = tid >> 6;
    const int l32  = lane & 31;
    const int hx   = lane >> 5;

    const int srow  = tid >> 3;
    const int sslot = (tid & 7) ^ (srow & 7);

    int ok;
    {
        int i = tid * 4;
        i32x4 mv = *(const i32x4*)(maskg + b * S_LEN + i);
        bf16x4 bb;
        ok = 1;
        #pragma unroll
        for (int r = 0; r < 4; ++r) {
            ok &= (mv[r] != 0);
            bb[r] = mv[r] ? (bf16)0.f : (bf16)(-3.0e38f);
        }
        *(bf16x4*)&bias_lds[i] = bb;
    }
    const int allvalid = __syncthreads_and(ok);

    bf16x8 qf[4];
    {
        const bf16* qrow = qg + (size_t)(b * S_LEN + q0 + w * 32 + l32) * EMB + h * HDIM + hx * 8;
        qf[0] = *(const bf16x8*)(qrow);
        qf[1] = *(const bf16x8*)(qrow + 16);
        qf[2] = *(const bf16x8*)(qrow + 32);
        qf[3] = *(const bf16x8*)(qrow + 48);
    }

    const bf16* kgb = kg  + (size_t)b * S_LEN * EMB + h * HDIM;
    const bf16* vgb = vtg + (size_t)((b * NHEAD + h) * HDIM) * S_LEN;

    float mrow = -1e30f, lpart = 0.f;
    f32x16 o0, o1;
    #pragma unroll
    for (int r = 0; r < 16; ++r) { o0[r] = 0.f; o1[r] = 0.f; }

#define STAGE(BUF, KT) {                                                            \
    gload_lds16(kgb + (size_t)((KT) * 64 + srow) * EMB + sslot * 8,                 \
                &klds[BUF][tid * 8]);                                               \
    gload_lds16(vgb + (size_t)srow * S_LEN + (KT) * 64 + sslot * 8,                 \
                &vlds[BUF][tid * 8]);                                               \
}

#define LDSK(CUR, ROW, SB) (*(const bf16x8*)((const char*)&klds[CUR][0] + ((ROW) << 7) + ((((SB) ^ ((ROW) & 7))) << 4)))
#define LDSV(CUR, ROW, SB) (*(const bf16x8*)((const char*)&vlds[CUR][0] + ((ROW) << 7) + ((((SB) ^ ((ROW) & 7))) << 4)))

#define SUBTILE(CUR, KT, KK) {                                                      \
    f32x16 s_;                                                                      \
    _Pragma("unroll") for (int r_ = 0; r_ < 16; ++r_) s_[r_] = 0.f;                 \
    const int krow_ = (KK) * 32 + l32;                                              \
    __builtin_amdgcn_s_setprio(1);                                                  \
    s_ = MFMA32(LDSK(CUR, krow_, 0 * 2 + hx), qf[0], s_);                           \
    s_ = MFMA32(LDSK(CUR, krow_, 1 * 2 + hx), qf[1], s_);                           \
    s_ = MFMA32(LDSK(CUR, krow_, 2 * 2 + hx), qf[2], s_);                           \
    s_ = MFMA32(LDSK(CUR, krow_, 3 * 2 + hx), qf[3], s_);                           \
    __builtin_amdgcn_s_setprio(0);                                                  \
    if (!allvalid) {                                                                \
        _Pragma("unroll") for (int s4_ = 0; s4_ < 4; ++s4_) {                       \
            bf16x4 b4_ = *(const bf16x4*)&bias_lds[(KT) * 64 + (KK) * 32 + s4_ * 8 + hx * 4]; \
            _Pragma("unroll") for (int t_ = 0; t_ < 4; ++t_)                        \
                s_[4 * s4_ + t_] += (float)b4_[t_];                                 \
        }                                                                           \
    }                                                                               \
    float rmax_ = s_[0];                                                            \
    _Pragma("unroll") for (int r_ = 1; r_ < 16; ++r_) rmax_ = fmaxf(rmax_, s_[r_]); \
    rmax_ = fmaxf(rmax_, __shfl_xor(rmax_, 32));                                    \
    if (!__all(rmax_ <= mrow + 8.f)) {                                              \
        float mnew_  = fmaxf(mrow, rmax_);                                          \
        float alpha_ = __builtin_amdgcn_exp2f(mrow - mnew_);                        \
        mrow = mnew_; lpart *= alpha_;                                              \
        if (hx == 0) stat_lds[w][l32] = alpha_;                                     \
        _Pragma("unroll") for (int s4_ = 0; s4_ < 4; ++s4_) {                       \
            f32x4 a4_ = *(const f32x4*)&stat_lds[w][s4_ * 8 + hx * 4];              \
            _Pragma("unroll") for (int t_ = 0; t_ < 4; ++t_) {                      \
                o0[4 * s4_ + t_] *= a4_[t_]; o1[4 * s4_ + t_] *= a4_[t_];           \
            }                                                                       \
        }                                                                           \
    }                                                                               \
    bf16x8 pa0, pa1;                                                                \
    {                                                                               \
        float p_[8];                                                                \
        _Pragma("unroll") for (int r_ = 0; r_ < 8; ++r_) {                          \
            p_[r_] = __builtin_amdgcn_exp2f(s_[r_] - mrow); lpart += p_[r_];        \
        }                                                                           \
        i32x2 r0_ = permswap(pkbf(p_[0], p_[1]), pkbf(p_[4], p_[5]));               \
        i32x2 r1_ = permswap(pkbf(p_[2], p_[3]), pkbf(p_[6], p_[7]));               \
        i32x4 fw_; fw_[0] = r0_[0]; fw_[1] = r1_[0]; fw_[2] = r0_[1]; fw_[3] = r1_[1]; \
        pa0 = __builtin_bit_cast(bf16x8, fw_);                                      \
    }                                                                               \
    {                                                                               \
        float p_[8];                                                                \
        _Pragma("unroll") for (int r_ = 0; r_ < 8; ++r_) {                          \
            p_[r_] = __builtin_amdgcn_exp2f(s_[8 + r_] - mrow); lpart += p_[r_];    \
        }                                                                           \
        i32x2 r0_ = permswap(pkbf(p_[0], p_[1]), pkbf(p_[4], p_[5]));               \
        i32x2 r1_ = permswap(pkbf(p_[2], p_[3]), pkbf(p_[6], p_[7]));               \
        i32x4 fw_; fw_[0] = r0_[0]; fw_[1] = r1_[0]; fw_[2] = r0_[1]; fw_[3] = r1_[1]; \
        pa1 = __builtin_bit_cast(bf16x8, fw_);                                      \
    }                                                                               \
    __builtin_amdgcn_s_setprio(1);                                                  \
    o0 = MFMA32(pa0, LDSV(CUR, 0 * 32 + l32, (KK) * 4 + 0 * 2 + hx), o0);           \
    o1 = MFMA32(pa0, LDSV(CUR, 1 * 32 + l32, (KK) * 4 + 0 * 2 + hx), o1);           \
    o0 = MFMA32(pa1, LDSV(CUR, 0 * 32 + l32, (KK) * 4 + 1 * 2 + hx), o0);           \
    o1 = MFMA32(pa1, LDSV(CUR, 1 * 32 + l32, (KK) * 4 + 1 * 2 + hx), o1);           \
    __builtin_amdgcn_s_setprio(0);                                                  \
}

    STAGE(0, 0)
    __syncthreads();

    for (int kt = 0; kt < 32; ++kt) {
        const int cur = kt & 1;
        if (kt + 1 < 32) STAGE(cur ^ 1, kt + 1)
        SUBTILE(cur, kt, 0)
        SUBTILE(cur, kt, 1)
        __syncthreads();
    }

#undef SUBTILE
#undef LDSK
#undef LDSV
#undef STAGE

    float lrow = lpart + __shfl_xor(lpart, 32);
    float inv  = lrow > 0.f ? 1.f / lrow : 0.f;
    if (hx == 0) stat_lds[w][l32] = inv;
    #pragma unroll
    for (int s4 = 0; s4 < 4; ++s4) {
        f32x4 i4 = *(const f32x4*)&stat_lds[w][s4 * 8 + hx * 4];
        #pragma unroll
        for (int t = 0; t < 4; ++t) {
            size_t row = (size_t)(b * S_LEN + q0 + w * 32 + s4 * 8 + hx * 4 + t);
            bf16* cp = ctx + row * EMB + h * HDIM + l32;
            cp[0]  = (bf16)(o0[4 * s4 + t] * i4[t]);
            cp[32] = (bf16)(o1[4 * s4 + t] * i4[t]);
        }
    }
}

extern "C" void kernel_launch(void* const* d_in, const int* in_sizes, int n_in,
                              void* d_out, int out_size, void* d_ws, size_t ws_size,
                              hipStream_t stream)
{
    const float* x   = (const float*)d_in[0];
    const int*  mask = (const int*)d_in[1];
    const float* Wq  = (const float*)d_in[2];
    const float* bq  = (const float*)d_in[3];
    const float* Wk  = (const float*)d_in[4];
    const float* bk  = (const float*)d_in[5];
    const float* Wv  = (const float*)d_in[6];
    const float* bv  = (const float*)d_in[7];
    const float* Wo  = (const float*)d_in[8];
    const float* bo  = (const float*)d_in[9];
    (void)in_sizes; (void)n_in; (void)out_size; (void)ws_size;

    const size_t me = (size_t)NTOK * EMB;    // 8.4M
    const size_t we = (size_t)EMB * EMB;     // 1M
    bf16* xb  = (bf16*)d_ws;
    bf16* qb  = xb  + me;
    bf16* kb  = qb  + me;
    bf16* vt  = kb  + me;     // V transposed [b,h,d,s]
    bf16* wqb = vt  + me;     // [4][we] contiguous: wq, wk, wv, wo
    bf16* wkb = wqb + we;
    bf16* wvb = wkb + we;
    bf16* wob = wvb + we;
    bf16* cx  = xb;           // alias: xb consumed by qkv gemm before flash writes cx

    cvt_f32_bf16<<<(int)(me / 4 / 256), 256, 0, stream>>>(x, xb, (int)(me / 4));
    cvt_w4<<<dim3((int)(we / 4 / 256), 4), 256, 0, stream>>>(Wq, Wk, Wv, Wo, wqb);

    // q_scale = 1/sqrt(HDIM) * log2(e), folded into Q so flash softmax is scale-free
    gemm_bt<<<dim3(1536), 256, 0, stream>>>(
        xb, wqb, wkb, wvb, bq, bk, bv, qb, kb, vt, 1, 0.18033688011112042f);

    flash_attn<<<dim3(512), 512, 0, stream>>>(qb, kb, vt, mask, cx);

    gemm_bt<<<dim3(512), 256, 0, stream>>>(
        cx, wob, wob, wob, bo, bo, bo, d_out, d_out, d_out, 0, 1.0f);
}